// Round 2
// baseline (661.493 us; speedup 1.0000x reference)
//
#include <hip/hip_runtime.h>

// Problem constants: B=4, H=W=256, C=64, OC=64, K=3, PAD=1
#define FEAT_N (4*64*256*256)
#define OFFS_N (4*18*256*256)
#define WTF_N  (576*64)            // deform weights, bf16, MFMA-B-fragment order
#define WT2_N  (576*20)            // offset-conv weights transposed [ic*9+t][oc pad 20]

typedef __attribute__((ext_vector_type(8))) short short8;
typedef __attribute__((ext_vector_type(4))) float float4v;

__device__ __forceinline__ unsigned short f2bf(float f) {
    union { float f; unsigned u; } c; c.f = f;
    unsigned r = c.u + 0x7FFF + ((c.u >> 16) & 1);   // RNE
    return (unsigned short)(r >> 16);
}

// ---------------------------------------------------------------------------
// Weight prep: deform weights -> bf16 B-fragment order [ks][nt][lane][8],
// offset-conv weights -> [ic*9+t][oc pad 20] fp32.
// B-frag element (ks,nt,lane,j): B[k][n], k=ks*32+(lane>>4)*8+j, n=nt*16+(lane&15)
// with k = tap*64+ic, B[k][n] = dw[n*576 + ic*9 + tap].
// ---------------------------------------------------------------------------
__global__ __launch_bounds__(256) void prep_weights(const float* __restrict__ dw,
                                                    const float* __restrict__ ow,
                                                    unsigned short* __restrict__ wtf,
                                                    float* __restrict__ wt2) {
    int idx = blockIdx.x * 256 + threadIdx.x;
    if (idx < WTF_N) {
        int j    = idx & 7;
        int lane = (idx >> 3) & 63;
        int nt   = (idx >> 9) & 3;
        int ks   = idx >> 11;
        int k    = ks * 32 + ((lane >> 4) << 3) + j;
        int tap  = k >> 6;
        int ic   = k & 63;
        int n    = nt * 16 + (lane & 15);
        wtf[idx] = f2bf(dw[n * 576 + ic * 9 + tap]);
    }
    int i2 = idx - WTF_N;
    if (i2 >= 0 && i2 < WT2_N) {
        int t  = i2 / 20;
        int oc = i2 - t * 20;
        wt2[i2] = (oc < 18) ? ow[oc * 576 + t] : 0.f;
    }
}

// ---------------------------------------------------------------------------
// conv1: x[4,3,256,256] * w[64,3,3,3] + b -> feat, pad=1  (unchanged)
// ---------------------------------------------------------------------------
__global__ __launch_bounds__(256) void conv1_kernel(const float* __restrict__ x,
                                                    const float* __restrict__ cw,
                                                    const float* __restrict__ cb,
                                                    float* __restrict__ feat) {
    __shared__ __align__(16) float wl[64 * 28];
    __shared__ float bl[64];
    const int tid = threadIdx.x;
    for (int i = tid; i < 64 * 28; i += 256) {
        int oc = i / 28;
        int t  = i - oc * 28;
        wl[i] = (t < 27) ? cw[oc * 27 + t] : 0.f;
    }
    if (tid < 64) bl[tid] = cb[tid];
    __syncthreads();

    const int bx = blockIdx.x;
    const int b  = bx >> 7;
    const int h0 = (bx & 127) << 1;
    const int w  = tid;

    float xr[3][4][3];
#pragma unroll
    for (int ic = 0; ic < 3; ic++) {
#pragma unroll
        for (int r = 0; r < 4; r++) {
            int row = h0 - 1 + r;
            bool rok = (unsigned)row < 256u;
#pragma unroll
            for (int j = 0; j < 3; j++) {
                int col = w - 1 + j;
                bool ok = rok && ((unsigned)col < 256u);
                xr[ic][r][j] = ok ? x[((b * 3 + ic) << 16) + (row << 8) + col] : 0.f;
            }
        }
    }

    for (int oc = 0; oc < 64; oc++) {
        float aA = bl[oc];
        float aB = aA;
        const float* wp = &wl[oc * 28];
#pragma unroll
        for (int ic = 0; ic < 3; ic++) {
#pragma unroll
            for (int i = 0; i < 3; i++) {
#pragma unroll
                for (int j = 0; j < 3; j++) {
                    float wv = wp[ic * 9 + i * 3 + j];
                    aA += xr[ic][i][j] * wv;
                    aB += xr[ic][i + 1][j] * wv;
                }
            }
        }
        int o = ((b * 64 + oc) << 16) + (h0 << 8) + w;
        feat[o]       = aA;
        feat[o + 256] = aB;
    }
}

// ---------------------------------------------------------------------------
// conv2: feat * ow[18,64,3,3] + ob -> offs, pad=1  (unchanged)
// ---------------------------------------------------------------------------
__global__ __launch_bounds__(256) void conv2_kernel(const float* __restrict__ feat,
                                                    const float* __restrict__ wt2,
                                                    const float* __restrict__ ob,
                                                    float* __restrict__ offs) {
    __shared__ __align__(16) float w2[WT2_N];
    const int tid = threadIdx.x;
    {
        const float4* s4 = (const float4*)wt2;
        float4* d4 = (float4*)w2;
        for (int i = tid; i < WT2_N / 4; i += 256) d4[i] = s4[i];
    }
    __syncthreads();

    const int bx = blockIdx.x;
    const int b  = bx >> 7;
    const int h0 = (bx & 127) << 1;
    const int w  = tid;

    float accA[20], accB[20];
#pragma unroll
    for (int q = 0; q < 20; q++) {
        float bv = (q < 18) ? ob[q] : 0.f;
        accA[q] = bv;
        accB[q] = bv;
    }

    for (int ic = 0; ic < 64; ic++) {
        const float* fp = feat + ((size_t)(b * 64 + ic) << 16);
        float rv[4][3];
#pragma unroll
        for (int r = 0; r < 4; r++) {
            int row = h0 - 1 + r;
            bool rok = (unsigned)row < 256u;
#pragma unroll
            for (int j = 0; j < 3; j++) {
                int col = w - 1 + j;
                rv[r][j] = (rok && ((unsigned)col < 256u)) ? fp[(row << 8) + col] : 0.f;
            }
        }
        const float4* wrow = (const float4*)&w2[ic * 180];
#pragma unroll
        for (int t = 0; t < 9; t++) {
            const int i = t / 3, j = t - (t / 3) * 3;
            float fA = rv[i][j];
            float fB = rv[i + 1][j];
#pragma unroll
            for (int q = 0; q < 5; q++) {
                float4 wv = wrow[t * 5 + q];
                accA[q * 4 + 0] += fA * wv.x; accA[q * 4 + 1] += fA * wv.y;
                accA[q * 4 + 2] += fA * wv.z; accA[q * 4 + 3] += fA * wv.w;
                accB[q * 4 + 0] += fB * wv.x; accB[q * 4 + 1] += fB * wv.y;
                accB[q * 4 + 2] += fB * wv.z; accB[q * 4 + 3] += fB * wv.w;
            }
        }
    }

#pragma unroll
    for (int oc = 0; oc < 18; oc++) {
        int o = ((b * 18 + oc) << 16) + (h0 << 8) + w;
        offs[o]       = accA[oc];
        offs[o + 256] = accB[oc];
    }
}

// ---------------------------------------------------------------------------
// deform conv, MFMA version. Block = 256 thr = 4 waves; block tile = 128 px
// (half row, fixed b,ho) x 64 oc; K = 9 taps * 64 ic = 576.
// Each wave: 32 px = 2 M-tiles, all 4 N-tiles. A-fragments are built in
// registers straight from bilinear gathers (no LDS, no barriers in K-loop).
// B-fragments are frag-ready bf16 in global (L1/L2 resident, 73 KB).
// A layout: A[m=lane&15][k=quad*8+j]; B: B[k=quad*8+j][n=lane&15];
// D: n=lane&15, m=quad*4+reg  (verified gfx950 mappings).
// ---------------------------------------------------------------------------
__global__ __launch_bounds__(256) void deform_kernel(const float* __restrict__ feat,
                                                     const float* __restrict__ offs,
                                                     const unsigned short* __restrict__ wtf,
                                                     const float* __restrict__ db,
                                                     float* __restrict__ out) {
    __shared__ __align__(16) float st[4 * 64 * 33];   // per-wave [64oc][32px pad33]
    const int tid  = threadIdx.x;
    const int lane = tid & 63;
    const int wave = tid >> 6;
    const int lm   = lane & 15;
    const int quad = lane >> 4;

    const int bx = blockIdx.x;
    const int wo_base = (bx & 1) << 7;
    const int ho = (bx >> 1) & 255;
    const int b  = bx >> 9;

    const int wo0 = wo_base + wave * 32 + lm;   // mt=0 pixel
    const int wo1 = wo0 + 16;                   // mt=1 pixel

    float4v acc[2][4];
#pragma unroll
    for (int mt = 0; mt < 2; mt++)
#pragma unroll
        for (int nt = 0; nt < 4; nt++) acc[mt][nt] = (float4v)0.f;

    const float* fb = feat + ((size_t)b << 22);                 // b*64*65536
    const float* ob = offs + (((size_t)b * 18) << 16) + (ho << 8);

    for (int tap = 0; tap < 9; ++tap) {
        const int ky = tap / 3;
        const int kx = tap - 3 * ky;

        int   A00[2], A01[2], A10[2], A11[2];
        float W00[2], W01[2], W10[2], W11[2];
#pragma unroll
        for (int mt = 0; mt < 2; mt++) {
            const int wo = mt ? wo1 : wo0;
            float offy = ob[((2 * tap) << 16) + wo];
            float offx = ob[((2 * tap + 1) << 16) + wo];
            float sy = (float)(ho - 1 + ky) + offy;
            float sx = (float)(wo - 1 + kx) + offx;
            float y0f = floorf(sy), x0f = floorf(sx);
            float dy = sy - y0f, dx = sx - x0f;
            int y0 = (int)y0f, x0 = (int)x0f;
            bool vy0 = (unsigned)y0 < 256u;
            bool vy1 = (unsigned)(y0 + 1) < 256u;
            bool vx0 = (unsigned)x0 < 256u;
            bool vx1 = (unsigned)(x0 + 1) < 256u;
            int yi0 = y0 < 0 ? 0 : (y0 > 255 ? 255 : y0);
            int yi1 = (y0 + 1) < 0 ? 0 : ((y0 + 1) > 255 ? 255 : (y0 + 1));
            int xi0 = x0 < 0 ? 0 : (x0 > 255 ? 255 : x0);
            int xi1 = (x0 + 1) < 0 ? 0 : ((x0 + 1) > 255 ? 255 : (x0 + 1));
            float w00 = (1.f - dy) * (1.f - dx); if (!(vy0 && vx0)) w00 = 0.f;
            float w01 = (1.f - dy) * dx;         if (!(vy0 && vx1)) w01 = 0.f;
            float w10 = dy * (1.f - dx);         if (!(vy1 && vx0)) w10 = 0.f;
            float w11 = dy * dx;                 if (!(vy1 && vx1)) w11 = 0.f;
            A00[mt] = (yi0 << 8) + xi0; A01[mt] = (yi0 << 8) + xi1;
            A10[mt] = (yi1 << 8) + xi0; A11[mt] = (yi1 << 8) + xi1;
            W00[mt] = w00; W01[mt] = w01; W10[mt] = w10; W11[mt] = w11;
        }

#pragma unroll
        for (int step = 0; step < 2; ++step) {
            const int ks = tap * 2 + step;
            short8 bfr[4];
            const unsigned short* wp = wtf + (size_t)(ks * 256 + lane) * 8;
#pragma unroll
            for (int nt = 0; nt < 4; nt++)
                bfr[nt] = *(const short8*)(wp + (nt << 9));

            const float* pc = fb + ((size_t)(step * 32 + (quad << 3)) << 16);
#pragma unroll
            for (int mt = 0; mt < 2; mt++) {
                union { short8 v; unsigned short u[8]; } af;
#pragma unroll
                for (int jj = 0; jj < 8; jj++) {
                    const float* p = pc + ((size_t)jj << 16);
                    float g = W00[mt] * p[A00[mt]] + W01[mt] * p[A01[mt]]
                            + W10[mt] * p[A10[mt]] + W11[mt] * p[A11[mt]];
                    af.u[jj] = f2bf(g);
                }
#pragma unroll
                for (int nt = 0; nt < 4; nt++)
                    acc[mt][nt] = __builtin_amdgcn_mfma_f32_16x16x32_bf16(
                        af.v, bfr[nt], acc[mt][nt], 0, 0, 0);
            }
        }
    }

    // epilogue: per-wave transpose through LDS, then px-contiguous stores
    float* sw = &st[wave * 64 * 33];
#pragma unroll
    for (int mt = 0; mt < 2; mt++)
#pragma unroll
        for (int nt = 0; nt < 4; nt++)
#pragma unroll
            for (int reg = 0; reg < 4; reg++) {
                int ocl = nt * 16 + lm;
                int pxl = mt * 16 + quad * 4 + reg;
                sw[ocl * 33 + pxl] = acc[mt][nt][reg];
            }
    __syncthreads();

    const int ochalf = lane >> 5;        // 0 or 1
    const int pxs    = lane & 31;
    const int wob    = wo_base + wave * 32 + pxs;
    float* outb = out + (((size_t)b * 64) << 16) + (ho << 8) + wob;
#pragma unroll 8
    for (int i = 0; i < 32; i++) {
        int oc = i * 2 + ochalf;
        outb[(size_t)oc << 16] = sw[oc * 33 + pxs] + db[oc];
    }
}

// ---------------------------------------------------------------------------
extern "C" void kernel_launch(void* const* d_in, const int* in_sizes, int n_in,
                              void* d_out, int out_size, void* d_ws, size_t ws_size,
                              hipStream_t stream) {
    const float* x  = (const float*)d_in[0];
    const float* cw = (const float*)d_in[1];
    const float* cb = (const float*)d_in[2];
    const float* ow = (const float*)d_in[3];
    const float* ob = (const float*)d_in[4];
    const float* dw = (const float*)d_in[5];
    const float* db = (const float*)d_in[6];
    float* out = (float*)d_out;

    float* feat  = (float*)d_ws;                 // 64 MB
    float* offsb = feat + FEAT_N;                // 18 MB
    unsigned short* wtf = (unsigned short*)(offsb + OFFS_N);   // 72 KB bf16 frags
    float* wt2 = (float*)(wtf + WTF_N);          // 45 KB

    prep_weights<<<189, 256, 0, stream>>>(dw, ow, wtf, wt2);
    conv1_kernel<<<512, 256, 0, stream>>>(x, cw, cb, feat);
    conv2_kernel<<<512, 256, 0, stream>>>(feat, wt2, ob, offsb);
    deform_kernel<<<2048, 256, 0, stream>>>(feat, offsb, wtf, db, out);
}

// Round 3
// 554.074 us; speedup vs baseline: 1.1939x; 1.1939x over previous
//
#include <hip/hip_runtime.h>

// Problem constants: B=4, H=W=256, C=64, OC=64, K=3, PAD=1
#define FEAT_N (4*64*256*256)
#define OFFS_N (4*18*256*256)
#define WTF_N  (576*64)            // deform weights, bf16, MFMA-B-fragment order
#define WT2_N  (576*20)            // offset-conv weights transposed [ic*9+t][oc pad 20]

typedef __attribute__((ext_vector_type(8))) short short8;
typedef __attribute__((ext_vector_type(4))) float float4v;

__device__ __forceinline__ unsigned short f2bf(float f) {
    union { float f; unsigned u; } c; c.f = f;
    unsigned r = c.u + 0x7FFF + ((c.u >> 16) & 1);   // RNE
    return (unsigned short)(r >> 16);
}

// ---------------------------------------------------------------------------
// Weight prep (unchanged from R2)
// ---------------------------------------------------------------------------
__global__ __launch_bounds__(256) void prep_weights(const float* __restrict__ dw,
                                                    const float* __restrict__ ow,
                                                    unsigned short* __restrict__ wtf,
                                                    float* __restrict__ wt2) {
    int idx = blockIdx.x * 256 + threadIdx.x;
    if (idx < WTF_N) {
        int j    = idx & 7;
        int lane = (idx >> 3) & 63;
        int nt   = (idx >> 9) & 3;
        int ks   = idx >> 11;
        int k    = ks * 32 + ((lane >> 4) << 3) + j;
        int tap  = k >> 6;
        int ic   = k & 63;
        int n    = nt * 16 + (lane & 15);
        wtf[idx] = f2bf(dw[n * 576 + ic * 9 + tap]);
    }
    int i2 = idx - WTF_N;
    if (i2 >= 0 && i2 < WT2_N) {
        int t  = i2 / 20;
        int oc = i2 - t * 20;
        wt2[i2] = (oc < 18) ? ow[oc * 576 + t] : 0.f;
    }
}

// ---------------------------------------------------------------------------
// conv1 (unchanged)
// ---------------------------------------------------------------------------
__global__ __launch_bounds__(256) void conv1_kernel(const float* __restrict__ x,
                                                    const float* __restrict__ cw,
                                                    const float* __restrict__ cb,
                                                    float* __restrict__ feat) {
    __shared__ __align__(16) float wl[64 * 28];
    __shared__ float bl[64];
    const int tid = threadIdx.x;
    for (int i = tid; i < 64 * 28; i += 256) {
        int oc = i / 28;
        int t  = i - oc * 28;
        wl[i] = (t < 27) ? cw[oc * 27 + t] : 0.f;
    }
    if (tid < 64) bl[tid] = cb[tid];
    __syncthreads();

    const int bx = blockIdx.x;
    const int b  = bx >> 7;
    const int h0 = (bx & 127) << 1;
    const int w  = tid;

    float xr[3][4][3];
#pragma unroll
    for (int ic = 0; ic < 3; ic++) {
#pragma unroll
        for (int r = 0; r < 4; r++) {
            int row = h0 - 1 + r;
            bool rok = (unsigned)row < 256u;
#pragma unroll
            for (int j = 0; j < 3; j++) {
                int col = w - 1 + j;
                bool ok = rok && ((unsigned)col < 256u);
                xr[ic][r][j] = ok ? x[((b * 3 + ic) << 16) + (row << 8) + col] : 0.f;
            }
        }
    }

    for (int oc = 0; oc < 64; oc++) {
        float aA = bl[oc];
        float aB = aA;
        const float* wp = &wl[oc * 28];
#pragma unroll
        for (int ic = 0; ic < 3; ic++) {
#pragma unroll
            for (int i = 0; i < 3; i++) {
#pragma unroll
                for (int j = 0; j < 3; j++) {
                    float wv = wp[ic * 9 + i * 3 + j];
                    aA += xr[ic][i][j] * wv;
                    aB += xr[ic][i + 1][j] * wv;
                }
            }
        }
        int o = ((b * 64 + oc) << 16) + (h0 << 8) + w;
        feat[o]       = aA;
        feat[o + 256] = aB;
    }
}

// ---------------------------------------------------------------------------
// conv2 (unchanged)
// ---------------------------------------------------------------------------
__global__ __launch_bounds__(256) void conv2_kernel(const float* __restrict__ feat,
                                                    const float* __restrict__ wt2,
                                                    const float* __restrict__ ob,
                                                    float* __restrict__ offs) {
    __shared__ __align__(16) float w2[WT2_N];
    const int tid = threadIdx.x;
    {
        const float4* s4 = (const float4*)wt2;
        float4* d4 = (float4*)w2;
        for (int i = tid; i < WT2_N / 4; i += 256) d4[i] = s4[i];
    }
    __syncthreads();

    const int bx = blockIdx.x;
    const int b  = bx >> 7;
    const int h0 = (bx & 127) << 1;
    const int w  = tid;

    float accA[20], accB[20];
#pragma unroll
    for (int q = 0; q < 20; q++) {
        float bv = (q < 18) ? ob[q] : 0.f;
        accA[q] = bv;
        accB[q] = bv;
    }

    for (int ic = 0; ic < 64; ic++) {
        const float* fp = feat + ((size_t)(b * 64 + ic) << 16);
        float rv[4][3];
#pragma unroll
        for (int r = 0; r < 4; r++) {
            int row = h0 - 1 + r;
            bool rok = (unsigned)row < 256u;
#pragma unroll
            for (int j = 0; j < 3; j++) {
                int col = w - 1 + j;
                rv[r][j] = (rok && ((unsigned)col < 256u)) ? fp[(row << 8) + col] : 0.f;
            }
        }
        const float4* wrow = (const float4*)&w2[ic * 180];
#pragma unroll
        for (int t = 0; t < 9; t++) {
            const int i = t / 3, j = t - (t / 3) * 3;
            float fA = rv[i][j];
            float fB = rv[i + 1][j];
#pragma unroll
            for (int q = 0; q < 5; q++) {
                float4 wv = wrow[t * 5 + q];
                accA[q * 4 + 0] += fA * wv.x; accA[q * 4 + 1] += fA * wv.y;
                accA[q * 4 + 2] += fA * wv.z; accA[q * 4 + 3] += fA * wv.w;
                accB[q * 4 + 0] += fB * wv.x; accB[q * 4 + 1] += fB * wv.y;
                accB[q * 4 + 2] += fB * wv.z; accB[q * 4 + 3] += fB * wv.w;
            }
        }
    }

#pragma unroll
    for (int oc = 0; oc < 18; oc++) {
        int o = ((b * 18 + oc) << 16) + (h0 << 8) + w;
        offs[o]       = accA[oc];
        offs[o + 256] = accB[oc];
    }
}

// ---------------------------------------------------------------------------
// deform conv, MFMA, zero-LDS. Block = 256 thr = 4 waves; tile = 128 px x 64 oc.
// XCD-swizzled block ids: each XCD owns a contiguous band of 256 strips so the
// 9-tap feat reuse stays in that XCD's 4 MB L2.
// A: m=lane&15 (px), k=quad*8+j (ic); B: n=lane&15 (oc), k=quad*8+j;
// D: m=quad*4+reg (px, contiguous!), n=lane&15 (oc) -> direct float4 stores.
// ---------------------------------------------------------------------------
__global__ __launch_bounds__(256) void deform_kernel(const float* __restrict__ feat,
                                                     const float* __restrict__ offs,
                                                     const unsigned short* __restrict__ wtf,
                                                     const float* __restrict__ db,
                                                     float* __restrict__ out) {
    const int tid  = threadIdx.x;
    const int lane = tid & 63;
    const int wave = tid >> 6;
    const int lm   = lane & 15;
    const int quad = lane >> 4;

    // XCD-aware swizzle: hw maps bx -> XCD bx&7 (round-robin). Give each XCD a
    // contiguous band of strips: strip = (bx&7)*256 + (bx>>3).
    const int bx = blockIdx.x;
    const int strip = ((bx & 7) << 8) | (bx >> 3);
    const int wo_base = (strip & 1) << 7;
    const int ho = (strip >> 1) & 255;
    const int b  = strip >> 9;

    const int wo0 = wo_base + wave * 32 + lm;   // mt=0 pixel
    const int wo1 = wo0 + 16;                   // mt=1 pixel

    float4v acc[2][4];
#pragma unroll
    for (int mt = 0; mt < 2; mt++)
#pragma unroll
        for (int nt = 0; nt < 4; nt++) acc[mt][nt] = (float4v)0.f;

    const float* fb = feat + ((size_t)b << 22);
    const float* opb = offs + (((size_t)b * 18) << 16) + (ho << 8);

    for (int tap = 0; tap < 9; ++tap) {
        const int ky = tap / 3;
        const int kx = tap - 3 * ky;

        int   A00[2], A01[2], A10[2], A11[2];
        float W00[2], W01[2], W10[2], W11[2];
#pragma unroll
        for (int mt = 0; mt < 2; mt++) {
            const int wo = mt ? wo1 : wo0;
            float offy = opb[((2 * tap) << 16) + wo];
            float offx = opb[((2 * tap + 1) << 16) + wo];
            float sy = (float)(ho - 1 + ky) + offy;
            float sx = (float)(wo - 1 + kx) + offx;
            float y0f = floorf(sy), x0f = floorf(sx);
            float dy = sy - y0f, dx = sx - x0f;
            int y0 = (int)y0f, x0 = (int)x0f;
            bool vy0 = (unsigned)y0 < 256u;
            bool vy1 = (unsigned)(y0 + 1) < 256u;
            bool vx0 = (unsigned)x0 < 256u;
            bool vx1 = (unsigned)(x0 + 1) < 256u;
            int yi0 = y0 < 0 ? 0 : (y0 > 255 ? 255 : y0);
            int yi1 = (y0 + 1) < 0 ? 0 : ((y0 + 1) > 255 ? 255 : (y0 + 1));
            int xi0 = x0 < 0 ? 0 : (x0 > 255 ? 255 : x0);
            int xi1 = (x0 + 1) < 0 ? 0 : ((x0 + 1) > 255 ? 255 : (x0 + 1));
            float w00 = (1.f - dy) * (1.f - dx); if (!(vy0 && vx0)) w00 = 0.f;
            float w01 = (1.f - dy) * dx;         if (!(vy0 && vx1)) w01 = 0.f;
            float w10 = dy * (1.f - dx);         if (!(vy1 && vx0)) w10 = 0.f;
            float w11 = dy * dx;                 if (!(vy1 && vx1)) w11 = 0.f;
            A00[mt] = (yi0 << 8) + xi0; A01[mt] = (yi0 << 8) + xi1;
            A10[mt] = (yi1 << 8) + xi0; A11[mt] = (yi1 << 8) + xi1;
            W00[mt] = w00; W01[mt] = w01; W10[mt] = w10; W11[mt] = w11;
        }

#pragma unroll
        for (int step = 0; step < 2; ++step) {
            const int ks = tap * 2 + step;
            short8 bfr[4];
            const unsigned short* wp = wtf + (size_t)(ks * 256 + lane) * 8;
#pragma unroll
            for (int nt = 0; nt < 4; nt++)
                bfr[nt] = *(const short8*)(wp + (nt << 9));

            const float* pc = fb + ((size_t)(step * 32 + (quad << 3)) << 16);

            // issue ALL 64 gathers (both M-tiles) before converting -> max MLP
            float r[2][8][4];
#pragma unroll
            for (int mt = 0; mt < 2; mt++)
#pragma unroll
                for (int jj = 0; jj < 8; jj++) {
                    const float* p = pc + ((size_t)jj << 16);
                    r[mt][jj][0] = p[A00[mt]];
                    r[mt][jj][1] = p[A01[mt]];
                    r[mt][jj][2] = p[A10[mt]];
                    r[mt][jj][3] = p[A11[mt]];
                }
#pragma unroll
            for (int mt = 0; mt < 2; mt++) {
                union { short8 v; unsigned short u[8]; } af;
#pragma unroll
                for (int jj = 0; jj < 8; jj++) {
                    float g = W00[mt] * r[mt][jj][0] + W01[mt] * r[mt][jj][1]
                            + W10[mt] * r[mt][jj][2] + W11[mt] * r[mt][jj][3];
                    af.u[jj] = f2bf(g);
                }
#pragma unroll
                for (int nt = 0; nt < 4; nt++)
                    acc[mt][nt] = __builtin_amdgcn_mfma_f32_16x16x32_bf16(
                        af.v, bfr[nt], acc[mt][nt], 0, 0, 0);
            }
        }
    }

    // epilogue: direct coalesced float4 stores (D: m=quad*4+reg consecutive px)
#pragma unroll
    for (int nt = 0; nt < 4; nt++) {
        int oc = nt * 16 + lm;
        float bv = db[oc];
        float* op = out + (((size_t)(b * 64 + oc)) << 16) + (ho << 8)
                  + wo_base + wave * 32 + quad * 4;
#pragma unroll
        for (int mt = 0; mt < 2; mt++) {
            float4 v = {acc[mt][nt][0] + bv, acc[mt][nt][1] + bv,
                        acc[mt][nt][2] + bv, acc[mt][nt][3] + bv};
            *(float4*)(op + mt * 16) = v;
        }
    }
}

// ---------------------------------------------------------------------------
extern "C" void kernel_launch(void* const* d_in, const int* in_sizes, int n_in,
                              void* d_out, int out_size, void* d_ws, size_t ws_size,
                              hipStream_t stream) {
    const float* x  = (const float*)d_in[0];
    const float* cw = (const float*)d_in[1];
    const float* cb = (const float*)d_in[2];
    const float* ow = (const float*)d_in[3];
    const float* ob = (const float*)d_in[4];
    const float* dw = (const float*)d_in[5];
    const float* db = (const float*)d_in[6];
    float* out = (float*)d_out;

    float* feat  = (float*)d_ws;                 // 64 MB
    float* offsb = feat + FEAT_N;                // 18 MB
    unsigned short* wtf = (unsigned short*)(offsb + OFFS_N);   // 72 KB bf16 frags
    float* wt2 = (float*)(wtf + WTF_N);          // 45 KB

    prep_weights<<<189, 256, 0, stream>>>(dw, ow, wtf, wt2);
    conv1_kernel<<<512, 256, 0, stream>>>(x, cw, cb, feat);
    conv2_kernel<<<512, 256, 0, stream>>>(feat, wt2, ob, offsb);
    deform_kernel<<<2048, 256, 0, stream>>>(feat, offsb, wtf, db, out);
}

// Round 4
// 494.265 us; speedup vs baseline: 1.3383x; 1.1210x over previous
//
#include <hip/hip_runtime.h>

// Problem constants: B=4, H=W=256, C=64, OC=64, K=3, PAD=1
#define FEAT_N (4*64*256*256)
#define OFFS_N (4*18*256*256)
#define WTF_N  (576*64)            // deform weights, bf16, MFMA-B-fragment order
#define WT2_N  (576*20)            // offset-conv weights transposed [ic*9+t][oc pad 20]

typedef __attribute__((ext_vector_type(8))) short short8;
typedef __attribute__((ext_vector_type(4))) float float4v;

__device__ __forceinline__ unsigned short f2bf(float f) {
    union { float f; unsigned u; } c; c.f = f;
    unsigned r = c.u + 0x7FFF + ((c.u >> 16) & 1);   // RNE
    return (unsigned short)(r >> 16);
}

// ---------------------------------------------------------------------------
// Weight prep (unchanged)
// ---------------------------------------------------------------------------
__global__ __launch_bounds__(256) void prep_weights(const float* __restrict__ dw,
                                                    const float* __restrict__ ow,
                                                    unsigned short* __restrict__ wtf,
                                                    float* __restrict__ wt2) {
    int idx = blockIdx.x * 256 + threadIdx.x;
    if (idx < WTF_N) {
        int j    = idx & 7;
        int lane = (idx >> 3) & 63;
        int nt   = (idx >> 9) & 3;
        int ks   = idx >> 11;
        int k    = ks * 32 + ((lane >> 4) << 3) + j;
        int tap  = k >> 6;
        int ic   = k & 63;
        int n    = nt * 16 + (lane & 15);
        wtf[idx] = f2bf(dw[n * 576 + ic * 9 + tap]);
    }
    int i2 = idx - WTF_N;
    if (i2 >= 0 && i2 < WT2_N) {
        int t  = i2 / 20;
        int oc = i2 - t * 20;
        wt2[i2] = (oc < 18) ? ow[oc * 576 + t] : 0.f;
    }
}

// ---------------------------------------------------------------------------
// conv1 (unchanged)
// ---------------------------------------------------------------------------
__global__ __launch_bounds__(256) void conv1_kernel(const float* __restrict__ x,
                                                    const float* __restrict__ cw,
                                                    const float* __restrict__ cb,
                                                    float* __restrict__ feat) {
    __shared__ __align__(16) float wl[64 * 28];
    __shared__ float bl[64];
    const int tid = threadIdx.x;
    for (int i = tid; i < 64 * 28; i += 256) {
        int oc = i / 28;
        int t  = i - oc * 28;
        wl[i] = (t < 27) ? cw[oc * 27 + t] : 0.f;
    }
    if (tid < 64) bl[tid] = cb[tid];
    __syncthreads();

    const int bx = blockIdx.x;
    const int b  = bx >> 7;
    const int h0 = (bx & 127) << 1;
    const int w  = tid;

    float xr[3][4][3];
#pragma unroll
    for (int ic = 0; ic < 3; ic++) {
#pragma unroll
        for (int r = 0; r < 4; r++) {
            int row = h0 - 1 + r;
            bool rok = (unsigned)row < 256u;
#pragma unroll
            for (int j = 0; j < 3; j++) {
                int col = w - 1 + j;
                bool ok = rok && ((unsigned)col < 256u);
                xr[ic][r][j] = ok ? x[((b * 3 + ic) << 16) + (row << 8) + col] : 0.f;
            }
        }
    }

    for (int oc = 0; oc < 64; oc++) {
        float aA = bl[oc];
        float aB = aA;
        const float* wp = &wl[oc * 28];
#pragma unroll
        for (int ic = 0; ic < 3; ic++) {
#pragma unroll
            for (int i = 0; i < 3; i++) {
#pragma unroll
                for (int j = 0; j < 3; j++) {
                    float wv = wp[ic * 9 + i * 3 + j];
                    aA += xr[ic][i][j] * wv;
                    aB += xr[ic][i + 1][j] * wv;
                }
            }
        }
        int o = ((b * 64 + oc) << 16) + (h0 << 8) + w;
        feat[o]       = aA;
        feat[o + 256] = aB;
    }
}

// ---------------------------------------------------------------------------
// conv2 (unchanged)
// ---------------------------------------------------------------------------
__global__ __launch_bounds__(256) void conv2_kernel(const float* __restrict__ feat,
                                                    const float* __restrict__ wt2,
                                                    const float* __restrict__ ob,
                                                    float* __restrict__ offs) {
    __shared__ __align__(16) float w2[WT2_N];
    const int tid = threadIdx.x;
    {
        const float4* s4 = (const float4*)wt2;
        float4* d4 = (float4*)w2;
        for (int i = tid; i < WT2_N / 4; i += 256) d4[i] = s4[i];
    }
    __syncthreads();

    const int bx = blockIdx.x;
    const int b  = bx >> 7;
    const int h0 = (bx & 127) << 1;
    const int w  = tid;

    float accA[20], accB[20];
#pragma unroll
    for (int q = 0; q < 20; q++) {
        float bv = (q < 18) ? ob[q] : 0.f;
        accA[q] = bv;
        accB[q] = bv;
    }

    for (int ic = 0; ic < 64; ic++) {
        const float* fp = feat + ((size_t)(b * 64 + ic) << 16);
        float rv[4][3];
#pragma unroll
        for (int r = 0; r < 4; r++) {
            int row = h0 - 1 + r;
            bool rok = (unsigned)row < 256u;
#pragma unroll
            for (int j = 0; j < 3; j++) {
                int col = w - 1 + j;
                rv[r][j] = (rok && ((unsigned)col < 256u)) ? fp[(row << 8) + col] : 0.f;
            }
        }
        const float4* wrow = (const float4*)&w2[ic * 180];
#pragma unroll
        for (int t = 0; t < 9; t++) {
            const int i = t / 3, j = t - (t / 3) * 3;
            float fA = rv[i][j];
            float fB = rv[i + 1][j];
#pragma unroll
            for (int q = 0; q < 5; q++) {
                float4 wv = wrow[t * 5 + q];
                accA[q * 4 + 0] += fA * wv.x; accA[q * 4 + 1] += fA * wv.y;
                accA[q * 4 + 2] += fA * wv.z; accA[q * 4 + 3] += fA * wv.w;
                accB[q * 4 + 0] += fB * wv.x; accB[q * 4 + 1] += fB * wv.y;
                accB[q * 4 + 2] += fB * wv.z; accB[q * 4 + 3] += fB * wv.w;
            }
        }
    }

#pragma unroll
    for (int oc = 0; oc < 18; oc++) {
        int o = ((b * 18 + oc) << 16) + (h0 << 8) + w;
        offs[o]       = accA[oc];
        offs[o + 256] = accB[oc];
    }
}

// ---------------------------------------------------------------------------
// deform conv, MFMA + coalesced LDS sampling.
// Block = 256 thr = 4 waves; tile = 128 px x 64 oc; K = 9 taps * 64 ic.
// Sampling role: thread = (px = tid&127, half = tid>>7 -> 32 channels);
//   lanes sweep consecutive pixels -> contiguous float2 bursts (both x-corners
//   in one 8B load; border handled by per-lane coefficients c0/c1).
//   Results -> bf16 LDS smp[buf][px][72] (double-buffered, 1 barrier/tap).
// MFMA role: A-frag = ds_read_b128 at [px][step*32+quad*8]; B-frag from
//   frag-ready global wtf (L1-hot). D: m=quad*4+reg px -> direct f4 stores.
// XCD swizzle keeps each XCD's feat band L2-resident (R3: FETCH 893->43 MB).
// ---------------------------------------------------------------------------
__global__ __launch_bounds__(256) void deform_kernel(const float* __restrict__ feat,
                                                     const float* __restrict__ offs,
                                                     const unsigned short* __restrict__ wtf,
                                                     const float* __restrict__ db,
                                                     float* __restrict__ out) {
    __shared__ __align__(16) unsigned short smp[2][128 * 72];
    const int tid  = threadIdx.x;
    const int lane = tid & 63;
    const int wave = tid >> 6;
    const int lm   = lane & 15;
    const int quad = lane >> 4;

    const int bx = blockIdx.x;
    const int strip = ((bx & 7) << 8) | (bx >> 3);
    const int wo_base = (strip & 1) << 7;
    const int ho = (strip >> 1) & 255;
    const int b  = strip >> 9;

    // sampler role
    const int px_s = tid & 127;
    const int half = tid >> 7;
    const int wo_s = wo_base + px_s;

    float4v acc[2][4];
#pragma unroll
    for (int mt = 0; mt < 2; mt++)
#pragma unroll
        for (int nt = 0; nt < 4; nt++) acc[mt][nt] = (float4v)0.f;

    const float* fb  = feat + ((size_t)b << 22) + (((size_t)half * 32) << 16);
    const float* opb = offs + (((size_t)b * 18) << 16) + (ho << 8) + wo_s;

    for (int tap = 0; tap < 9; ++tap) {
        const int ky = tap / 3;
        const int kx = tap - 3 * ky;

        // ---- per-pixel sample coords & folded border coefficients ----
        float offy = opb[(size_t)(2 * tap) << 16];
        float offx = opb[(size_t)(2 * tap + 1) << 16];
        float sy = (float)(ho - 1 + ky) + offy;
        float sx = (float)(wo_s - 1 + kx) + offx;
        float y0f = floorf(sy), x0f = floorf(sx);
        float dy = sy - y0f, dx = sx - x0f;
        int y0 = (int)y0f, x0 = (int)x0f;
        float wy0 = ((unsigned)y0 < 256u) ? (1.f - dy) : 0.f;
        float wy1 = ((unsigned)(y0 + 1) < 256u) ? dy : 0.f;
        // float2 window starts at xb=clamp(x0,0,255): e0=x[xb], e1=x[xb+1]
        float c0 = ((unsigned)x0 < 256u) ? (1.f - dx) : ((x0 == -1) ? dx : 0.f);
        float c1 = ((unsigned)x0 < 255u) ? dx : 0.f;   // x0 in [0,254]
        int yb0 = y0 < 0 ? 0 : (y0 > 255 ? 255 : y0);
        int yb1 = (y0 + 1) < 0 ? 0 : ((y0 + 1) > 255 ? 255 : (y0 + 1));
        int xb  = x0 < 0 ? 0 : (x0 > 255 ? 255 : x0);
        const int r0 = (yb0 << 8) + xb;
        const int r1 = (yb1 << 8) + xb;

        unsigned short* sb = &smp[tap & 1][px_s * 72 + half * 32];
#pragma unroll 8
        for (int i = 0; i < 16; i++) {
            const float* p0 = fb + ((size_t)(2 * i) << 16);
            const float* p1 = fb + ((size_t)(2 * i + 1) << 16);
            float2 a0 = *(const float2*)(p0 + r0);
            float2 b0 = *(const float2*)(p0 + r1);
            float2 a1 = *(const float2*)(p1 + r0);
            float2 b1 = *(const float2*)(p1 + r1);
            float g0 = wy0 * (c0 * a0.x + c1 * a0.y) + wy1 * (c0 * b0.x + c1 * b0.y);
            float g1 = wy0 * (c0 * a1.x + c1 * a1.y) + wy1 * (c0 * b1.x + c1 * b1.y);
            unsigned pk = (unsigned)f2bf(g0) | ((unsigned)f2bf(g1) << 16);
            *(unsigned*)(sb + 2 * i) = pk;
        }
        __syncthreads();

        // ---- consume: 2 K-steps x 2 M-tiles x 4 N-tiles MFMA ----
        const unsigned short* sbase = smp[tap & 1];
#pragma unroll
        for (int step = 0; step < 2; ++step) {
            const int ks = tap * 2 + step;
            short8 bfr[4];
            const unsigned short* wp = wtf + (size_t)(ks * 256 + lane) * 8;
#pragma unroll
            for (int nt = 0; nt < 4; nt++)
                bfr[nt] = *(const short8*)(wp + (nt << 9));
#pragma unroll
            for (int mt = 0; mt < 2; mt++) {
                int px = wave * 32 + mt * 16 + lm;
                short8 af = *(const short8*)(sbase + px * 72 + step * 32 + quad * 8);
#pragma unroll
                for (int nt = 0; nt < 4; nt++)
                    acc[mt][nt] = __builtin_amdgcn_mfma_f32_16x16x32_bf16(
                        af, bfr[nt], acc[mt][nt], 0, 0, 0);
            }
        }
    }

    // epilogue: direct coalesced float4 stores (D: m=quad*4+reg consecutive px)
#pragma unroll
    for (int nt = 0; nt < 4; nt++) {
        int oc = nt * 16 + lm;
        float bv = db[oc];
        float* op = out + (((size_t)(b * 64 + oc)) << 16) + (ho << 8)
                  + wo_base + wave * 32 + quad * 4;
#pragma unroll
        for (int mt = 0; mt < 2; mt++) {
            float4 v = {acc[mt][nt][0] + bv, acc[mt][nt][1] + bv,
                        acc[mt][nt][2] + bv, acc[mt][nt][3] + bv};
            *(float4*)(op + mt * 16) = v;
        }
    }
}

// ---------------------------------------------------------------------------
extern "C" void kernel_launch(void* const* d_in, const int* in_sizes, int n_in,
                              void* d_out, int out_size, void* d_ws, size_t ws_size,
                              hipStream_t stream) {
    const float* x  = (const float*)d_in[0];
    const float* cw = (const float*)d_in[1];
    const float* cb = (const float*)d_in[2];
    const float* ow = (const float*)d_in[3];
    const float* ob = (const float*)d_in[4];
    const float* dw = (const float*)d_in[5];
    const float* db = (const float*)d_in[6];
    float* out = (float*)d_out;

    float* feat  = (float*)d_ws;                 // 64 MB
    float* offsb = feat + FEAT_N;                // 18 MB
    unsigned short* wtf = (unsigned short*)(offsb + OFFS_N);   // 72 KB bf16 frags
    float* wt2 = (float*)(wtf + WTF_N);          // 45 KB

    prep_weights<<<189, 256, 0, stream>>>(dw, ow, wtf, wt2);
    conv1_kernel<<<512, 256, 0, stream>>>(x, cw, cb, feat);
    conv2_kernel<<<512, 256, 0, stream>>>(feat, wt2, ob, offsb);
    deform_kernel<<<2048, 256, 0, stream>>>(feat, offsb, wtf, db, out);
}